// Round 9
// baseline (479.612 us; speedup 1.0000x reference)
//
#include <hip/hip_runtime.h>
#include <hip/hip_bf16.h>

#define BSZ 32
#define TT 50
#define TS 49
#define PH 101   // sSH pitch in kseq

// ---- ws layout (float offsets) ----
#define OFF_GPRE  0u         // 32*49*400 = 627200
#define OFF_QL    627200u    // 32*49*8             -> 639744
#define OFF_IDX   639744u    // 32*49*10 ints       -> 655424
#define OFF_NV    655424u    // 32*49 ints          -> 656992
#define OFF_QSC   656992u    // 32*49*500           -> 1440992 (~5.76 MB)

#define RLF(v,l) __uint_as_float(__builtin_amdgcn_readlane(__float_as_uint(v), (l)))

__device__ __forceinline__ float tanh_fast(float x) {
    float e = __expf(2.f * x);
    return 1.f - __fdividef(2.f, e + 1.f);
}
__device__ __forceinline__ float sigm_fast(float x) {
    return __fdividef(1.f, 1.f + __expf(-x));
}
__device__ __forceinline__ float dot4(float4 a, float4 b) {
    return a.x*b.x + a.y*b.y + a.z*b.z + a.w*b.w;
}

// ================= kab: dual aggregate (q||u halves) + fused tail =================
// One block per (b,t). Threads 0-255: q-aggregate; 256-511: u-aggregate
// (identical control flow -> block barriers align). Then fusion/GPRE/QSC/
// scores/QL/topk in the same block (R8 kfuse logic, re-laned for 512 thr).
__global__ __launch_bounds__(512) void kab(
    const int* __restrict__ user, const int* __restrict__ question,
    const int* __restrict__ response, const int* __restrict__ mask,
    const int* __restrict__ qnbr, const int* __restrict__ snbr,
    const int* __restrict__ unbr, const int* __restrict__ qnbr2,
    const int* __restrict__ qsidx,
    const float* __restrict__ embQ, const float* __restrict__ embQ2,
    const float* __restrict__ embS, const float* __restrict__ embU,
    const float* __restrict__ embR,
    const float* __restrict__ aggw, const float* __restrict__ aggb,
    const float* __restrict__ wlast, const float* __restrict__ blast,
    const float* __restrict__ w1p, const float* __restrict__ w2p,
    const float* __restrict__ wfus, const float* __restrict__ bfus,
    const float* __restrict__ wih, const float* __restrict__ bih, const float* __restrict__ bhh,
    const float* __restrict__ wq, const float* __restrict__ bq, const float* __restrict__ ww,
    float* __restrict__ WS)
{
    int bid = blockIdx.x;
    int b = bid / TS, t = bid - b*TS;
    int tid = threadIdx.x;
    int side = tid >> 8, ltid = tid & 255;
    size_t bt = (size_t)b*TS + t;

    // per-side aggregation pool (word offsets):
    // b2in 0..3888 | x1 3888..4536 | s2v1b 4536..5136 | v1a 5136..5736
    // x0 5736..5840 | v0a 5840..5944 | v0b 5944..6048
    __shared__ __align__(16) float POOL[2][6608];
    __shared__ int nbuf[2][264];        // n1 @0, n2 @8, n3 @48
    __shared__ __align__(16) float sE1[104], sE2[104];
    __shared__ __align__(16) float sEIN[200], sET[112], sEQN[104], sQSCm[500];
    __shared__ float sWW[104], sVQ[104], sScore[52], sCq[1];

    int mm  = mask[b*TT + t];
    int q_t = question[b*TT + t];
    int r_t = response[b*TT + t];
    int qn  = question[b*TT + t + 1];

    if (mm == 1) {
        // ---------------- aggregation (each half does one side) ----------------
        int root = side ? user[b*TT + t] : q_t;
        const int*    tabA = side ? unbr  : qnbr;
        const int*    tabB = side ? qnbr2 : snbr;
        const float4* eE   = (const float4*)(side ? embU  : embQ);
        const float4* eO   = (const float4*)(side ? embQ2 : embS);
        float* P     = POOL[side];
        float* b2in  = P;
        float* x1    = P + 3888;
        float* s2v1b = P + 4536;
        float* v1a   = P + 5136;
        float* x0    = P + 5736;
        float* v0a   = P + 5840;
        float* v0b   = P + 5944;
        int* n1 = nbuf[side];
        int* n2 = n1 + 8;
        int* n3 = n1 + 48;
        float* sEout = side ? sE2 : sE1;

        if (ltid < 6) n1[ltid] = tabA[root*6 + ltid];
        __syncthreads();
        if (ltid < 36) n2[ltid] = tabB[n1[ltid/6]*6 + (ltid % 6)];
        __syncthreads();
        if (ltid < 216) n3[ltid] = tabA[n2[ltid/6]*6 + (ltid % 6)];
        __syncthreads();
        // ---- float4 staging ----
        for (int i4 = ltid; i4 < 900; i4 += 256) {
            int v = i4 / 25, j = i4 - v*25;
            float4 a = eE[(size_t)n2[v]*25 + j];
            float4 s = make_float4(0.f, 0.f, 0.f, 0.f);
            const int* p = n3 + v*6;
            #pragma unroll
            for (int c = 0; c < 6; ++c) {
                float4 o = eO[(size_t)p[c]*25 + j];
                s.x += o.x; s.y += o.y; s.z += o.z; s.w += o.w;
            }
            float4 r = make_float4(a.x + s.x*(1.f/6.f), a.y + s.y*(1.f/6.f),
                                   a.z + s.z*(1.f/6.f), a.w + s.w*(1.f/6.f));
            *(float4*)(b2in + v*108 + 4*j) = r;
        }
        for (int i4 = ltid; i4 < 150; i4 += 256) {
            int a = i4 / 25, j = i4 - a*25;
            float4 base = eO[(size_t)n1[a]*25 + j];
            float4 s = make_float4(0.f, 0.f, 0.f, 0.f);
            #pragma unroll
            for (int c = 0; c < 6; ++c) {
                float4 o = eE[(size_t)n2[a*6 + c]*25 + j];
                s.x += o.x; s.y += o.y; s.z += o.z; s.w += o.w;
            }
            float4 r = make_float4(base.x + s.x*(1.f/6.f), base.y + s.y*(1.f/6.f),
                                   base.z + s.z*(1.f/6.f), base.w + s.w*(1.f/6.f));
            *(float4*)(x1 + a*108 + 4*j) = r;
        }
        if (ltid >= 160 && ltid < 185) {
            int j = ltid - 160;
            float4 base = eE[(size_t)root*25 + j];
            float4 s = make_float4(0.f, 0.f, 0.f, 0.f);
            #pragma unroll
            for (int a = 0; a < 6; ++a) {
                float4 o = eO[(size_t)n1[a]*25 + j];
                s.x += o.x; s.y += o.y; s.z += o.z; s.w += o.w;
            }
            float4 r = make_float4(base.x + s.x*(1.f/6.f), base.y + s.y*(1.f/6.f),
                                   base.z + s.z*(1.f/6.f), base.w + s.w*(1.f/6.f));
            *(float4*)(x0 + 4*j) = r;
        }
        __syncthreads();
        // ---- i=0: j2 (ltid<150: 4r x 6c), j1 (160-209: 2r x 6c), j0 (216-240: 4r) ----
        if (ltid < 150) {
            int dblk = ltid / 6, a = ltid - dblk*6, d0 = dblk*4;
            const float* wp = aggw + 20000 + d0*100;
            const float* xb = b2in + a*648;
            float acc[4][6];
            #pragma unroll
            for (int r = 0; r < 4; ++r)
                #pragma unroll
                for (int c = 0; c < 6; ++c) acc[r][c] = 0.f;
            #pragma unroll
            for (int j = 0; j < 25; ++j) {
                float4 r0 = *(const float4*)(wp + 4*j);
                float4 r1 = *(const float4*)(wp + 100 + 4*j);
                float4 r2 = *(const float4*)(wp + 200 + 4*j);
                float4 r3 = *(const float4*)(wp + 300 + 4*j);
                #pragma unroll
                for (int c = 0; c < 6; ++c) {
                    float4 x = *(const float4*)(xb + c*108 + 4*j);
                    acc[0][c] += dot4(r0, x);
                    acc[1][c] += dot4(r1, x);
                    acc[2][c] += dot4(r2, x);
                    acc[3][c] += dot4(r3, x);
                }
            }
            #pragma unroll
            for (int r = 0; r < 4; ++r) {
                float bia = aggb[200 + d0 + r];
                float o = 0.f;
                #pragma unroll
                for (int c = 0; c < 6; ++c) o += tanh_fast(bia + acc[r][c]);
                s2v1b[a*100 + d0 + r] = o;
            }
        } else if (ltid >= 160 && ltid < 210) {
            int d0 = (ltid - 160)*2;
            const float* wp = aggw + 10000 + d0*100;
            float a0[6], a1[6];
            #pragma unroll
            for (int c = 0; c < 6; ++c) { a0[c] = 0.f; a1[c] = 0.f; }
            #pragma unroll
            for (int j = 0; j < 25; ++j) {
                float4 r0 = *(const float4*)(wp + 4*j);
                float4 r1 = *(const float4*)(wp + 100 + 4*j);
                #pragma unroll
                for (int c = 0; c < 6; ++c) {
                    float4 x = *(const float4*)(x1 + c*108 + 4*j);
                    a0[c] += dot4(r0, x);
                    a1[c] += dot4(r1, x);
                }
            }
            #pragma unroll
            for (int c = 0; c < 6; ++c) {
                v1a[c*100 + d0]     = tanh_fast(aggb[100 + d0] + a0[c]);
                v1a[c*100 + d0 + 1] = tanh_fast(aggb[100 + d0 + 1] + a1[c]);
            }
        } else if (ltid >= 216 && ltid < 241) {
            int d0 = (ltid - 216)*4;
            const float* wp = aggw + d0*100;
            float a0 = 0.f, a1 = 0.f, a2 = 0.f, a3 = 0.f;
            #pragma unroll
            for (int j = 0; j < 25; ++j) {
                float4 x = *(const float4*)(x0 + 4*j);
                a0 += dot4(*(const float4*)(wp + 4*j), x);
                a1 += dot4(*(const float4*)(wp + 100 + 4*j), x);
                a2 += dot4(*(const float4*)(wp + 200 + 4*j), x);
                a3 += dot4(*(const float4*)(wp + 300 + 4*j), x);
            }
            v0a[d0]   = tanh_fast(aggb[d0] + a0);
            v0a[d0+1] = tanh_fast(aggb[d0+1] + a1);
            v0a[d0+2] = tanh_fast(aggb[d0+2] + a2);
            v0a[d0+3] = tanh_fast(aggb[d0+3] + a3);
        }
        __syncthreads();
        // ---- rebuild i=1 inputs ----
        for (int e = ltid; e < 600; e += 256) {
            int a = e / 100, d = e - a*100;
            x1[a*108 + d] = v1a[a*100 + d] + s2v1b[a*100 + d]*(1.f/6.f);
        }
        if (ltid >= 128 && ltid < 228) {
            int d = ltid - 128;
            float s = 0.f;
            #pragma unroll
            for (int a = 0; a < 6; ++a) s += v1a[a*100 + d];
            x0[d] = v0a[d] + s*(1.f/6.f);
        }
        __syncthreads();
        // ---- i=1: j1 (ltid<50 -> v1b in s2v1b), j0 (64-88 -> v0b) ----
        if (ltid < 50) {
            int d0 = ltid*2;
            const float* wp = aggw + 10000 + d0*100;
            float a0[6], a1[6];
            #pragma unroll
            for (int c = 0; c < 6; ++c) { a0[c] = 0.f; a1[c] = 0.f; }
            #pragma unroll
            for (int j = 0; j < 25; ++j) {
                float4 r0 = *(const float4*)(wp + 4*j);
                float4 r1 = *(const float4*)(wp + 100 + 4*j);
                #pragma unroll
                for (int c = 0; c < 6; ++c) {
                    float4 x = *(const float4*)(x1 + c*108 + 4*j);
                    a0[c] += dot4(r0, x);
                    a1[c] += dot4(r1, x);
                }
            }
            #pragma unroll
            for (int c = 0; c < 6; ++c) {
                s2v1b[c*100 + d0]     = tanh_fast(aggb[100 + d0] + a0[c]);
                s2v1b[c*100 + d0 + 1] = tanh_fast(aggb[100 + d0 + 1] + a1[c]);
            }
        } else if (ltid >= 64 && ltid < 89) {
            int d0 = (ltid - 64)*4;
            const float* wp = aggw + d0*100;
            float a0 = 0.f, a1 = 0.f, a2 = 0.f, a3 = 0.f;
            #pragma unroll
            for (int j = 0; j < 25; ++j) {
                float4 x = *(const float4*)(x0 + 4*j);
                a0 += dot4(*(const float4*)(wp + 4*j), x);
                a1 += dot4(*(const float4*)(wp + 100 + 4*j), x);
                a2 += dot4(*(const float4*)(wp + 200 + 4*j), x);
                a3 += dot4(*(const float4*)(wp + 300 + 4*j), x);
            }
            v0b[d0]   = tanh_fast(aggb[d0] + a0);
            v0b[d0+1] = tanh_fast(aggb[d0+1] + a1);
            v0b[d0+2] = tanh_fast(aggb[d0+2] + a2);
            v0b[d0+3] = tanh_fast(aggb[d0+3] + a3);
        }
        __syncthreads();
        // ---- i=2 input ----
        if (ltid < 100) {
            float s = 0.f;
            #pragma unroll
            for (int a = 0; a < 6; ++a) s += s2v1b[a*100 + ltid];
            x0[ltid] = v0b[ltid] + s*(1.f/6.f);
        }
        __syncthreads();
        if (ltid < 25) {
            int d0 = ltid*4;
            const float* wp = aggw + d0*100;
            float a0 = 0.f, a1 = 0.f, a2 = 0.f, a3 = 0.f;
            #pragma unroll
            for (int j = 0; j < 25; ++j) {
                float4 x = *(const float4*)(x0 + 4*j);
                a0 += dot4(*(const float4*)(wp + 4*j), x);
                a1 += dot4(*(const float4*)(wp + 100 + 4*j), x);
                a2 += dot4(*(const float4*)(wp + 200 + 4*j), x);
                a3 += dot4(*(const float4*)(wp + 300 + 4*j), x);
            }
            v0a[d0]   = tanh_fast(aggb[d0] + a0);
            v0a[d0+1] = tanh_fast(aggb[d0+1] + a1);
            v0a[d0+2] = tanh_fast(aggb[d0+2] + a2);
            v0a[d0+3] = tanh_fast(aggb[d0+3] + a3);
        }
        __syncthreads();
        if (ltid < 25) {
            int d0 = ltid*4;
            const float* wp = wlast + d0*100;
            float a0 = 0.f, a1 = 0.f, a2 = 0.f, a3 = 0.f;
            #pragma unroll
            for (int j = 0; j < 25; ++j) {
                float4 x = *(const float4*)(v0a + 4*j);
                a0 += dot4(*(const float4*)(wp + 4*j), x);
                a1 += dot4(*(const float4*)(wp + 100 + 4*j), x);
                a2 += dot4(*(const float4*)(wp + 200 + 4*j), x);
                a3 += dot4(*(const float4*)(wp + 300 + 4*j), x);
            }
            float4 r = make_float4(tanh_fast(blast[d0] + a0), tanh_fast(blast[d0+1] + a1),
                                   tanh_fast(blast[d0+2] + a2), tanh_fast(blast[d0+3] + a3));
            *(float4*)(sEout + d0) = r;
        }
    } else {
        // mask==0: E1/E2 = raw embedding rows of q_t
        if (tid < 25)
            ((float4*)sE1)[tid] = ((const float4*)embQ)[(size_t)q_t*25 + tid];
        else if (tid >= 256 && tid < 281)
            ((float4*)sE2)[tid - 256] = ((const float4*)embQ2)[(size_t)q_t*25 + (tid - 256)];
    }
    __syncthreads();

    // ---------------- tail: fusion + GPRE + predict precompute ----------------
    // T0: stage inputs
    if (tid < 100) {
        sEIN[tid] = w1p[0]*sE1[tid] + w2p[0]*sE2[tid];
    } else if (tid < 200) {
        sEIN[tid] = embR[r_t*100 + (tid - 100)];
    } else if (tid < 300) {
        sEQN[tid - 200] = embQ[(size_t)qn*100 + (tid - 200)];
    } else if (tid < 400) {
        sWW[tid - 300] = ww[tid - 300];
    } else if (tid < 500) {
        int i = tid - 400, q = i/25 + 1, j = i - (q-1)*25;
        float4 v = ((const float4*)embS)[(size_t)qsidx[qn*4 + (q-1)]*25 + j];
        *(float4*)(sQSCm + q*100 + 4*j) = v;
    }
    __syncthreads();
    // T1: fusion GEMV (tid<160) || vq/cq (160-255) || scores (256-304) || QSC commit (320-444)
    if (tid < 160) {
        int slot = tid >> 4, k0 = tid & 15;
        #pragma unroll
        for (int rp = 0; rp < 10; ++rp) {
            int row = rp*10 + slot;
            const float* wr = wfus + row*200;
            float acc = 0.f;
            #pragma unroll
            for (int m = 0; m < 4; ++m) {
                int f4i = k0 + 16*m;
                if (f4i < 50)
                    acc += dot4(*(const float4*)(wr + 4*f4i), *(const float4*)(sEIN + 4*f4i));
            }
            acc += __shfl_xor(acc, 1); acc += __shfl_xor(acc, 2);
            acc += __shfl_xor(acc, 4); acc += __shfl_xor(acc, 8);
            if (k0 == 0) sET[row] = fmaxf(acc + bfus[row], 0.f);
        }
    } else if (tid < 256) {
        for (int k = tid - 160; k < 100; k += 96) {
            float a = 0.f;
            for (int d = 0; d < 100; ++d) a += sWW[d] * wq[d*100 + k];
            sVQ[k] = a;
        }
        if (tid == 255) {
            float a = 0.f;
            for (int d = 0; d < 100; ++d) a += bq[d] * sWW[d];
            sCq[0] = a;
        }
    } else if (tid < 256 + TS) {
        int tp = tid - 256;
        if (tp < t) {
            int qq = question[b*TT + tp];
            const float* er = embQ + (size_t)qq*100;
            float acc = 0.f;
            #pragma unroll
            for (int k = 0; k < 25; ++k)
                acc += dot4(*(const float4*)(er + 4*k), *(const float4*)(sEQN + 4*k));
            sScore[tp] = acc;
        }
    } else if (tid >= 320 && tid < 445) {
        int i = tid - 320, q = i / 25, j = i - q*25;
        float4 v = (q == 0) ? *(const float4*)(sEQN + 4*j)
                            : *(const float4*)(sQSCm + q*100 + 4*j);
        if (q == 0) *(float4*)(sQSCm + 4*j) = v;
        *(float4*)(WS + OFF_QSC + bt*500 + q*100 + 4*j) = v;
    }
    __syncthreads();
    // T2: GPRE (all 512) + QL (384-463) + topk (wave 5)
    {
        int slot = tid >> 4, k0 = tid & 15;
        #pragma unroll
        for (int rp = 0; rp < 13; ++rp) {
            int row = rp*32 + slot;
            float acc = 0.f;
            if (row < 400) {
                const float* wr = wih + row*100;
                #pragma unroll
                for (int m = 0; m < 2; ++m) {
                    int f4i = k0 + 16*m;
                    if (f4i < 25)
                        acc += dot4(*(const float4*)(wr + 4*f4i), *(const float4*)(sET + 4*f4i));
                }
            }
            acc += __shfl_xor(acc, 1); acc += __shfl_xor(acc, 2);
            acc += __shfl_xor(acc, 4); acc += __shfl_xor(acc, 8);
            if (k0 == 0 && row < 400)
                WS[OFF_GPRE + bt*400 + row] = acc + bih[row] + bhh[row];
        }
    }
    if (tid >= 384 && tid < 464) {
        int q = (tid - 384) >> 4, kk = tid & 15;
        float acc = 0.f;
        #pragma unroll
        for (int j = 0; j < 7; ++j) {
            int k = kk + 16*j;
            if (k < 100) acc = fmaf(sQSCm[q*100 + k], sVQ[k], acc);
        }
        acc += __shfl_xor(acc, 1); acc += __shfl_xor(acc, 2);
        acc += __shfl_xor(acc, 4); acc += __shfl_xor(acc, 8);
        if (kk == 0) WS[OFF_QL + bt*8 + q] = acc + sCq[0];
    }
    if (tid >= 320 && tid < 384) {
        int lane = tid - 320;
        int nv = t < 10 ? t : 10;
        int* idxp = (int*)(WS + OFF_IDX) + bt*10;
        if (lane == 0) ((int*)(WS + OFF_NV))[bt] = nv;
        float v = (lane < t) ? sScore[lane] : -3.0e38f;
        int myidx = lane;
        int taken = 0;
        for (int p = 0; p < 10; ++p) {
            float vv = taken ? -3.0e38f : v;
            int ii = myidx;
            #pragma unroll
            for (int m = 1; m < 64; m <<= 1) {
                float v2 = __shfl_xor(vv, m);
                int   i2 = __shfl_xor(ii, m);
                if (v2 > vv || (v2 == vv && i2 < ii)) { vv = v2; ii = i2; }
            }
            if (p < nv) {
                if (lane == 0) idxp[p] = ii;
                if (myidx == ii) taken = 1;
            } else if (lane == 0) idxp[p] = 0;
        }
    }
}

// ================= kseq: 9 waves, 2 barriers/step (R8-identical + float4 preloads) =================
__global__ __launch_bounds__(576) void kseq(
    const int* __restrict__ mask, const float* __restrict__ whh,
    const float* __restrict__ wk, const float* __restrict__ bk,
    const float* __restrict__ ww, const float* __restrict__ bwp,
    const float* __restrict__ WS, float* __restrict__ out)
{
    int b = blockIdx.x, tid = threadIdx.x, lane = tid & 63;
    __shared__ __align__(16) float sQSCall[TS*500];
    __shared__ float sSH[TS*PH + 3];
    __shared__ __align__(16) float sQLall[TS*8];
    __shared__ int   sIdxAll[TS*10];
    __shared__ int   sNvAll[TS];
    __shared__ int   sMask[TT];
    __shared__ float sH[104], sC[104], sG[400], sVKl[104];
    __shared__ float sKL2[2][12], sGv2[2][64];
    __shared__ float sCk[1];

    size_t b0 = (size_t)b*TS;
    int g = tid - 64;
    bool isGate = (g >= 0 && g < 400);

    float4 wv[25];
    if (isGate) {
        #pragma unroll
        for (int j = 0; j < 25; ++j) wv[j] = *(const float4*)(whh + g*100 + 4*j);
    }
    float gpre = isGate ? WS[OFF_GPRE + b0*400 + g] : 0.f;

    {
        const float4* src = (const float4*)(WS + OFF_QSC + b0*500);
        for (int i4 = tid; i4 < 6125; i4 += 576) ((float4*)sQSCall)[i4] = src[i4];
        const float4* srq = (const float4*)(WS + OFF_QL + b0*8);
        for (int i4 = tid; i4 < 98; i4 += 576) ((float4*)sQLall)[i4] = srq[i4];
    }
    for (int i = tid; i < TS*10;  i += 576) sIdxAll[i] = ((const int*)(WS + OFF_IDX))[b0*10 + i];
    for (int i = tid; i < TS;     i += 576) sNvAll[i]  = ((const int*)(WS + OFF_NV))[b0 + i];
    if (tid < TT) sMask[tid] = mask[b*TT + tid];
    if (tid < 104) { sH[tid] = 0.f; sC[tid] = 0.f; }
    if (tid >= 104 && tid < 204) {
        int k = tid - 104;
        float a = 0.f;
        for (int d = 0; d < 100; ++d) a += ww[100 + d] * wk[d*100 + k];
        sVKl[k] = a;
    }
    if (tid == 204) {
        float a = 0.f;
        for (int d = 0; d < 100; ++d) a += bk[d] * ww[100 + d];
        sCk[0] = a;
    }
    if (tid == 205) out[b*TT] = 0.5f;
    float bw = bwp[0];
    __syncthreads();
    float ck = sCk[0];

    for (int t = 0; t < TS; ++t) {
        int par = t & 1;
        if (isGate) {
            float hA = sH[lane];
            float hB = sH[64 + (lane % 36)];
            float gpre_nx = 0.f;
            if (t + 1 < TS) gpre_nx = WS[OFF_GPRE + (b0 + t + 1)*400 + g];
            float a0 = 0.f, a1 = 0.f, a2 = 0.f, a3 = 0.f;
            #pragma unroll
            for (int j = 0; j < 25; ++j) {
                const int kb = 4*j;
                float h0, h1, h2, h3;
                if (kb < 64) {
                    h0 = RLF(hA, kb);   h1 = RLF(hA, kb+1);
                    h2 = RLF(hA, kb+2); h3 = RLF(hA, kb+3);
                } else {
                    h0 = RLF(hB, kb-64); h1 = RLF(hB, kb-63);
                    h2 = RLF(hB, kb-62); h3 = RLF(hB, kb-61);
                }
                a0 = fmaf(h0, wv[j].x, a0);
                a1 = fmaf(h1, wv[j].y, a1);
                a2 = fmaf(h2, wv[j].z, a2);
                a3 = fmaf(h3, wv[j].w, a3);
            }
            sG[g] = (a0 + a1) + (a2 + a3) + gpre;
            gpre = gpre_nx;
        } else if (tid >= 512) {
            // wave 8: 60 h-independent dots for step t
            int nv = sNvAll[t];
            if (lane < 60) {
                bool isKL = lane < 10;
                int s = isKL ? (lane + 1) : (((lane - 10) % 10) + 1);
                int q = isKL ? 0 : ((lane - 10) / 10);
                if (s <= nv) {
                    const float* st = sSH + sIdxAll[t*10 + s - 1]*PH;
                    const float* xp = isKL ? sVKl : (sQSCall + t*500 + q*100);
                    float c0 = 0.f, c1 = 0.f, c2 = 0.f, c3 = 0.f;
                    #pragma unroll
                    for (int k = 0; k < 100; k += 4) {
                        c0 = fmaf(st[k],   xp[k],   c0);
                        c1 = fmaf(st[k+1], xp[k+1], c1);
                        c2 = fmaf(st[k+2], xp[k+2], c2);
                        c3 = fmaf(st[k+3], xp[k+3], c3);
                    }
                    float acc = (c0 + c1) + (c2 + c3);
                    if (isKL) sKL2[par][s] = acc + ck;
                    else      sGv2[par][q*12 + s] = acc;
                }
            }
        } else if (tid < 64 && t > 0) {
            // wave 0: tail of step t-1
            int tau = t - 1, par2 = tau & 1;
            int nv = sNvAll[tau];
            int dd = lane >> 3, k0 = lane & 7;
            if (dd < 6) {
                const float* xp = (dd == 0) ? sVKl : (sQSCall + tau*500 + (dd-1)*100);
                float acc = 0.f;
                #pragma unroll
                for (int jj = 0; jj < 13; ++jj) {
                    int k = k0 + 8*jj;
                    if (k < 100) acc = fmaf(sH[k], xp[k], acc);
                }
                acc += __shfl_xor(acc, 1); acc += __shfl_xor(acc, 2); acc += __shfl_xor(acc, 4);
                if (k0 == 0) {
                    if (dd == 0) sKL2[par2][0] = acc + ck;
                    else         sGv2[par2][(dd-1)*12] = acc;
                }
            }
            int q = lane / 11, s = lane - q*11;
            bool valid = (lane < 55) && (s <= nv);
            float lg = valid ? (sQLall[tau*8 + q] + sKL2[par2][s] + bw) : 0.f;
            float e  = valid ? __expf(lg) : 0.f;
            float gv = valid ? sGv2[par2][q*12 + s] : 0.f;
            float se = e, sg = e*gv;
            #pragma unroll
            for (int m = 1; m < 64; m <<= 1) { se += __shfl_xor(se, m); sg += __shfl_xor(sg, m); }
            if (lane == 0) out[b*TT + tau + 1] = __fdividef(1.f, 1.f + __expf(-__fdividef(sg, se)));
        }
        __syncthreads();
        if (g >= 0 && g < 100) {
            float gi = sG[g], gf = sG[100+g], gg = sG[200+g], go = sG[300+g];
            float c2 = sigm_fast(gf)*sC[g] + sigm_fast(gi)*tanh_fast(gg);
            float h2 = sigm_fast(go)*tanh_fast(c2);
            if (sMask[t] == 1) { sH[g] = h2; sC[g] = c2; }
            sSH[t*PH + g] = sH[g];
        }
        __syncthreads();
    }
    // epilogue tail: tau = TS-1
    if (tid < 64) {
        int tau = TS - 1, par2 = tau & 1;
        int nv = sNvAll[tau];
        int dd = lane >> 3, k0 = lane & 7;
        if (dd < 6) {
            const float* xp = (dd == 0) ? sVKl : (sQSCall + tau*500 + (dd-1)*100);
            float acc = 0.f;
            #pragma unroll
            for (int jj = 0; jj < 13; ++jj) {
                int k = k0 + 8*jj;
                if (k < 100) acc = fmaf(sH[k], xp[k], acc);
            }
            acc += __shfl_xor(acc, 1); acc += __shfl_xor(acc, 2); acc += __shfl_xor(acc, 4);
            if (k0 == 0) {
                if (dd == 0) sKL2[par2][0] = acc + ck;
                else         sGv2[par2][(dd-1)*12] = acc;
            }
        }
        int q = lane / 11, s = lane - q*11;
        bool valid = (lane < 55) && (s <= nv);
        float lg = valid ? (sQLall[tau*8 + q] + sKL2[par2][s] + bw) : 0.f;
        float e  = valid ? __expf(lg) : 0.f;
        float gv = valid ? sGv2[par2][q*12 + s] : 0.f;
        float se = e, sg = e*gv;
        #pragma unroll
        for (int m = 1; m < 64; m <<= 1) { se += __shfl_xor(se, m); sg += __shfl_xor(sg, m); }
        if (lane == 0) out[b*TT + tau + 1] = __fdividef(1.f, 1.f + __expf(-__fdividef(sg, se)));
    }
}

extern "C" void kernel_launch(void* const* d_in, const int* in_sizes, int n_in,
                              void* d_out, int out_size, void* d_ws, size_t ws_size,
                              hipStream_t stream) {
    const int* user      = (const int*)d_in[0];
    const int* question  = (const int*)d_in[1];
    const int* response  = (const int*)d_in[2];
    const int* mask      = (const int*)d_in[3];
    const int* qnbr      = (const int*)d_in[4];
    const int* snbr      = (const int*)d_in[5];
    const int* unbr      = (const int*)d_in[6];
    const int* qnbr2     = (const int*)d_in[7];
    const int* qsidx     = (const int*)d_in[8];
    const float* embQ    = (const float*)d_in[9];
    const float* embQ2   = (const float*)d_in[10];
    const float* embS    = (const float*)d_in[11];
    const float* embU    = (const float*)d_in[12];
    const float* embR    = (const float*)d_in[13];
    const float* w1      = (const float*)d_in[14];
    const float* w2      = (const float*)d_in[15];
    const float* wih     = (const float*)d_in[16];
    const float* whh     = (const float*)d_in[17];
    const float* bih     = (const float*)d_in[18];
    const float* bhh     = (const float*)d_in[19];
    const float* aggw    = (const float*)d_in[20];
    const float* aggb    = (const float*)d_in[21];
    const float* wlast   = (const float*)d_in[22];
    const float* blast   = (const float*)d_in[23];
    const float* wq      = (const float*)d_in[24];
    const float* bq      = (const float*)d_in[25];
    const float* wk      = (const float*)d_in[26];
    const float* bk      = (const float*)d_in[27];
    const float* ww      = (const float*)d_in[28];
    const float* bwp     = (const float*)d_in[29];
    const float* wfus    = (const float*)d_in[30];
    const float* bfus    = (const float*)d_in[31];
    float* WS = (float*)d_ws;
    float* out = (float*)d_out;

    hipLaunchKernelGGL(kab, dim3(BSZ*TS), dim3(512), 0, stream,
                       user, question, response, mask, qnbr, snbr, unbr, qnbr2, qsidx,
                       embQ, embQ2, embS, embU, embR,
                       aggw, aggb, wlast, blast,
                       w1, w2, wfus, bfus, wih, bih, bhh, wq, bq, ww, WS);
    hipLaunchKernelGGL(kseq, dim3(BSZ), dim3(576), 0, stream,
                       mask, whh, wk, bk, ww, bwp, WS, out);
}

// Round 11
// 411.768 us; speedup vs baseline: 1.1648x; 1.1648x over previous
//
#include <hip/hip_runtime.h>
#include <hip/hip_bf16.h>

#define BSZ 32
#define TT 50
#define TS 49
#define PH 108   // sSH pitch: div by 4 (16B-aligned float4 rows), 108=4*27 -> rows spread banks

// ---- ws layout (float offsets) ----
#define OFF_GPRE  0u         // 32*49*400 = 627200
#define OFF_QL    627200u    // 32*49*8             -> 639744
#define OFF_IDX   639744u    // 32*49*10 ints       -> 655424
#define OFF_NV    655424u    // 32*49 ints          -> 656992
#define OFF_QSC   656992u    // 32*49*500           -> 1440992
#define OFF_E1    1440992u   // 32*49*100           -> 1597792
#define OFF_E2    1597792u   // 32*49*100           -> 1754592 (~7.02 MB)

#define RLF(v,l) __uint_as_float(__builtin_amdgcn_readlane(__float_as_uint(v), (l)))

__device__ __forceinline__ float tanh_fast(float x) {
    float e = __expf(2.f * x);
    return 1.f - __fdividef(2.f, e + 1.f);
}
__device__ __forceinline__ float sigm_fast(float x) {
    return __fdividef(1.f, 1.f + __expf(-x));
}
__device__ __forceinline__ float dot4(float4 a, float4 b) {
    return a.x*b.x + a.y*b.y + a.z*b.z + a.w*b.w;
}

// ================= kagg: one aggregate per block (R8-identical) =================
__global__ __launch_bounds__(256, 2) void kagg(
    const int* __restrict__ user, const int* __restrict__ question, const int* __restrict__ mask,
    const int* __restrict__ qnbr, const int* __restrict__ snbr,
    const int* __restrict__ unbr, const int* __restrict__ qnbr2,
    const float* __restrict__ embQ, const float* __restrict__ embQ2, const float* __restrict__ embS,
    const float* __restrict__ embU,
    const float* __restrict__ aggw, const float* __restrict__ aggb,
    const float* __restrict__ wlast, const float* __restrict__ blast,
    float* __restrict__ WS)
{
    int bid = blockIdx.x;
    int tid = threadIdx.x;

    int pair = bid >> 1, which = bid & 1;
    int b = pair / TS, t = pair - b*TS;
    int mm = mask[b*TT + t];
    float* outE = WS + (which ? OFF_E2 : OFF_E1) + (size_t)pair*100;

    if (mm != 1) {
        int q_t = question[b*TT + t];
        const float4* src = (const float4*)((which ? embQ2 : embQ) + (size_t)q_t*100);
        if (tid < 25) ((float4*)outE)[tid] = src[tid];
        return;
    }

    int root = which ? user[b*TT + t] : question[b*TT + t];
    const int*   tabA = which ? unbr  : qnbr;
    const int*   tabB = which ? qnbr2 : snbr;
    const float4* eE = (const float4*)(which ? embU  : embQ);
    const float4* eO = (const float4*)(which ? embQ2 : embS);

    __shared__ __align__(16) float b2in[36*108];
    __shared__ __align__(16) float x1[6*108];
    __shared__ float s2v1b[600];
    __shared__ float v1a[600];
    __shared__ __align__(16) float x0[104], v0a[104], v0b[104];
    __shared__ int n1[8], n2[36], n3[216];

    if (tid < 6) n1[tid] = tabA[root*6 + tid];
    __syncthreads();
    if (tid < 36) n2[tid] = tabB[n1[tid/6]*6 + (tid % 6)];
    __syncthreads();
    if (tid < 216) n3[tid] = tabA[n2[tid/6]*6 + (tid % 6)];
    __syncthreads();
    // ---- float4 staging ----
    for (int i4 = tid; i4 < 900; i4 += 256) {
        int v = i4 / 25, j = i4 - v*25;
        float4 a = eE[(size_t)n2[v]*25 + j];
        float4 s = make_float4(0.f, 0.f, 0.f, 0.f);
        const int* p = n3 + v*6;
        #pragma unroll
        for (int c = 0; c < 6; ++c) {
            float4 o = eO[(size_t)p[c]*25 + j];
            s.x += o.x; s.y += o.y; s.z += o.z; s.w += o.w;
        }
        float4 r = make_float4(a.x + s.x*(1.f/6.f), a.y + s.y*(1.f/6.f),
                               a.z + s.z*(1.f/6.f), a.w + s.w*(1.f/6.f));
        *(float4*)(b2in + v*108 + 4*j) = r;
    }
    for (int i4 = tid; i4 < 150; i4 += 256) {
        int a = i4 / 25, j = i4 - a*25;
        float4 base = eO[(size_t)n1[a]*25 + j];
        float4 s = make_float4(0.f, 0.f, 0.f, 0.f);
        #pragma unroll
        for (int c = 0; c < 6; ++c) {
            float4 o = eE[(size_t)n2[a*6 + c]*25 + j];
            s.x += o.x; s.y += o.y; s.z += o.z; s.w += o.w;
        }
        float4 r = make_float4(base.x + s.x*(1.f/6.f), base.y + s.y*(1.f/6.f),
                               base.z + s.z*(1.f/6.f), base.w + s.w*(1.f/6.f));
        *(float4*)(x1 + a*108 + 4*j) = r;
    }
    if (tid >= 160 && tid < 185) {
        int j = tid - 160;
        float4 base = eE[(size_t)root*25 + j];
        float4 s = make_float4(0.f, 0.f, 0.f, 0.f);
        #pragma unroll
        for (int a = 0; a < 6; ++a) {
            float4 o = eO[(size_t)n1[a]*25 + j];
            s.x += o.x; s.y += o.y; s.z += o.z; s.w += o.w;
        }
        float4 r = make_float4(base.x + s.x*(1.f/6.f), base.y + s.y*(1.f/6.f),
                               base.z + s.z*(1.f/6.f), base.w + s.w*(1.f/6.f));
        *(float4*)(x0 + 4*j) = r;
    }
    __syncthreads();
    // ---- i=0: j2 (tid<150: 4r x 6c), j1 (160-209: 2r x 6c), j0 (216-240: 4r) ----
    if (tid < 150) {
        int dblk = tid / 6, a = tid - dblk*6, d0 = dblk*4;
        const float* wp = aggw + 20000 + d0*100;
        const float* xb = b2in + a*648;
        float acc[4][6];
        #pragma unroll
        for (int r = 0; r < 4; ++r)
            #pragma unroll
            for (int c = 0; c < 6; ++c) acc[r][c] = 0.f;
        #pragma unroll
        for (int j = 0; j < 25; ++j) {
            float4 r0 = *(const float4*)(wp + 4*j);
            float4 r1 = *(const float4*)(wp + 100 + 4*j);
            float4 r2 = *(const float4*)(wp + 200 + 4*j);
            float4 r3 = *(const float4*)(wp + 300 + 4*j);
            #pragma unroll
            for (int c = 0; c < 6; ++c) {
                float4 x = *(const float4*)(xb + c*108 + 4*j);
                acc[0][c] += dot4(r0, x);
                acc[1][c] += dot4(r1, x);
                acc[2][c] += dot4(r2, x);
                acc[3][c] += dot4(r3, x);
            }
        }
        #pragma unroll
        for (int r = 0; r < 4; ++r) {
            float bia = aggb[200 + d0 + r];
            float o = 0.f;
            #pragma unroll
            for (int c = 0; c < 6; ++c) o += tanh_fast(bia + acc[r][c]);
            s2v1b[a*100 + d0 + r] = o;
        }
    } else if (tid >= 160 && tid < 210) {
        int d0 = (tid - 160)*2;
        const float* wp = aggw + 10000 + d0*100;
        float a0[6], a1[6];
        #pragma unroll
        for (int c = 0; c < 6; ++c) { a0[c] = 0.f; a1[c] = 0.f; }
        #pragma unroll
        for (int j = 0; j < 25; ++j) {
            float4 r0 = *(const float4*)(wp + 4*j);
            float4 r1 = *(const float4*)(wp + 100 + 4*j);
            #pragma unroll
            for (int c = 0; c < 6; ++c) {
                float4 x = *(const float4*)(x1 + c*108 + 4*j);
                a0[c] += dot4(r0, x);
                a1[c] += dot4(r1, x);
            }
        }
        #pragma unroll
        for (int c = 0; c < 6; ++c) {
            v1a[c*100 + d0]     = tanh_fast(aggb[100 + d0] + a0[c]);
            v1a[c*100 + d0 + 1] = tanh_fast(aggb[100 + d0 + 1] + a1[c]);
        }
    } else if (tid >= 216 && tid < 241) {
        int d0 = (tid - 216)*4;
        const float* wp = aggw + d0*100;
        float a0 = 0.f, a1 = 0.f, a2 = 0.f, a3 = 0.f;
        #pragma unroll
        for (int j = 0; j < 25; ++j) {
            float4 x = *(const float4*)(x0 + 4*j);
            a0 += dot4(*(const float4*)(wp + 4*j), x);
            a1 += dot4(*(const float4*)(wp + 100 + 4*j), x);
            a2 += dot4(*(const float4*)(wp + 200 + 4*j), x);
            a3 += dot4(*(const float4*)(wp + 300 + 4*j), x);
        }
        v0a[d0]   = tanh_fast(aggb[d0] + a0);
        v0a[d0+1] = tanh_fast(aggb[d0+1] + a1);
        v0a[d0+2] = tanh_fast(aggb[d0+2] + a2);
        v0a[d0+3] = tanh_fast(aggb[d0+3] + a3);
    }
    __syncthreads();
    // ---- rebuild i=1 inputs ----
    for (int e = tid; e < 600; e += 256) {
        int a = e / 100, d = e - a*100;
        x1[a*108 + d] = v1a[a*100 + d] + s2v1b[a*100 + d]*(1.f/6.f);
    }
    if (tid >= 128 && tid < 228) {
        int d = tid - 128;
        float s = 0.f;
        #pragma unroll
        for (int a = 0; a < 6; ++a) s += v1a[a*100 + d];
        x0[d] = v0a[d] + s*(1.f/6.f);
    }
    __syncthreads();
    // ---- i=1: j1 (tid<50 -> v1b in s2v1b), j0 (64-88 -> v0b) ----
    if (tid < 50) {
        int d0 = tid*2;
        const float* wp = aggw + 10000 + d0*100;
        float a0[6], a1[6];
        #pragma unroll
        for (int c = 0; c < 6; ++c) { a0[c] = 0.f; a1[c] = 0.f; }
        #pragma unroll
        for (int j = 0; j < 25; ++j) {
            float4 r0 = *(const float4*)(wp + 4*j);
            float4 r1 = *(const float4*)(wp + 100 + 4*j);
            #pragma unroll
            for (int c = 0; c < 6; ++c) {
                float4 x = *(const float4*)(x1 + c*108 + 4*j);
                a0[c] += dot4(r0, x);
                a1[c] += dot4(r1, x);
            }
        }
        #pragma unroll
        for (int c = 0; c < 6; ++c) {
            s2v1b[c*100 + d0]     = tanh_fast(aggb[100 + d0] + a0[c]);
            s2v1b[c*100 + d0 + 1] = tanh_fast(aggb[100 + d0 + 1] + a1[c]);
        }
    } else if (tid >= 64 && tid < 89) {
        int d0 = (tid - 64)*4;
        const float* wp = aggw + d0*100;
        float a0 = 0.f, a1 = 0.f, a2 = 0.f, a3 = 0.f;
        #pragma unroll
        for (int j = 0; j < 25; ++j) {
            float4 x = *(const float4*)(x0 + 4*j);
            a0 += dot4(*(const float4*)(wp + 4*j), x);
            a1 += dot4(*(const float4*)(wp + 100 + 4*j), x);
            a2 += dot4(*(const float4*)(wp + 200 + 4*j), x);
            a3 += dot4(*(const float4*)(wp + 300 + 4*j), x);
        }
        v0b[d0]   = tanh_fast(aggb[d0] + a0);
        v0b[d0+1] = tanh_fast(aggb[d0+1] + a1);
        v0b[d0+2] = tanh_fast(aggb[d0+2] + a2);
        v0b[d0+3] = tanh_fast(aggb[d0+3] + a3);
    }
    __syncthreads();
    // ---- i=2 input ----
    if (tid < 100) {
        float s = 0.f;
        #pragma unroll
        for (int a = 0; a < 6; ++a) s += s2v1b[a*100 + tid];
        x0[tid] = v0b[tid] + s*(1.f/6.f);
    }
    __syncthreads();
    if (tid < 25) {
        int d0 = tid*4;
        const float* wp = aggw + d0*100;
        float a0 = 0.f, a1 = 0.f, a2 = 0.f, a3 = 0.f;
        #pragma unroll
        for (int j = 0; j < 25; ++j) {
            float4 x = *(const float4*)(x0 + 4*j);
            a0 += dot4(*(const float4*)(wp + 4*j), x);
            a1 += dot4(*(const float4*)(wp + 100 + 4*j), x);
            a2 += dot4(*(const float4*)(wp + 200 + 4*j), x);
            a3 += dot4(*(const float4*)(wp + 300 + 4*j), x);
        }
        v0a[d0]   = tanh_fast(aggb[d0] + a0);
        v0a[d0+1] = tanh_fast(aggb[d0+1] + a1);
        v0a[d0+2] = tanh_fast(aggb[d0+2] + a2);
        v0a[d0+3] = tanh_fast(aggb[d0+3] + a3);
    }
    __syncthreads();
    if (tid < 25) {
        int d0 = tid*4;
        const float* wp = wlast + d0*100;
        float a0 = 0.f, a1 = 0.f, a2 = 0.f, a3 = 0.f;
        #pragma unroll
        for (int j = 0; j < 25; ++j) {
            float4 x = *(const float4*)(v0a + 4*j);
            a0 += dot4(*(const float4*)(wp + 4*j), x);
            a1 += dot4(*(const float4*)(wp + 100 + 4*j), x);
            a2 += dot4(*(const float4*)(wp + 200 + 4*j), x);
            a3 += dot4(*(const float4*)(wp + 300 + 4*j), x);
        }
        float4 r = make_float4(tanh_fast(blast[d0] + a0), tanh_fast(blast[d0+1] + a1),
                               tanh_fast(blast[d0+2] + a2), tanh_fast(blast[d0+3] + a3));
        *(float4*)(outE + d0) = r;
    }
}

// ================= kfuse: fusion + GPRE + predict precompute (R8-identical) =================
__global__ __launch_bounds__(256, 2) void kfuse(
    const int* __restrict__ question, const int* __restrict__ response,
    const int* __restrict__ qsidx,
    const float* __restrict__ embQ, const float* __restrict__ embS, const float* __restrict__ embR,
    const float* __restrict__ w1p, const float* __restrict__ w2p,
    const float* __restrict__ wfus, const float* __restrict__ bfus,
    const float* __restrict__ wih, const float* __restrict__ bih, const float* __restrict__ bhh,
    const float* __restrict__ wq, const float* __restrict__ bq, const float* __restrict__ ww,
    float* __restrict__ WS)
{
    int bid = blockIdx.x;
    int b = bid / TS, t = bid - b*TS;
    int tid = threadIdx.x;
    size_t bt = (size_t)b*TS + t;

    __shared__ __align__(16) float sEIN[200], sET[112], sEQN[104], sQSCm[500];
    __shared__ float sWW[104], sVQ[104], sScore[52], sCq[1];

    int r_t = response[b*TT + t];
    int qn  = question[b*TT + t + 1];
    // ---- phase0: stage inputs ----
    if (tid < 100) {
        sEIN[tid] = w1p[0]*WS[OFF_E1 + bt*100 + tid] + w2p[0]*WS[OFF_E2 + bt*100 + tid];
    } else if (tid < 200) {
        sEIN[tid] = embR[r_t*100 + (tid - 100)];
        if (tid < 150) {
            int d = tid - 100;
            sEQN[d]      = embQ[(size_t)qn*100 + d];
            sEQN[d + 50] = embQ[(size_t)qn*100 + d + 50];
        }
    } else {
        for (int i = tid - 200; i < 100; i += 56) sWW[i] = ww[i];
    }
    __syncthreads();
    // ---- phase1: fusion GEMV (tid<160, 16 lanes/row) || vq/cq (tid 160-255) ----
    if (tid < 160) {
        int slot = tid >> 4, k0 = tid & 15;
        #pragma unroll
        for (int rp = 0; rp < 10; ++rp) {
            int row = rp*10 + slot;
            const float* wr = wfus + row*200;
            float acc = 0.f;
            #pragma unroll
            for (int m = 0; m < 4; ++m) {
                int f4i = k0 + 16*m;
                if (f4i < 50)
                    acc += dot4(*(const float4*)(wr + 4*f4i), *(const float4*)(sEIN + 4*f4i));
            }
            acc += __shfl_xor(acc, 1); acc += __shfl_xor(acc, 2);
            acc += __shfl_xor(acc, 4); acc += __shfl_xor(acc, 8);
            if (k0 == 0) sET[row] = fmaxf(acc + bfus[row], 0.f);
        }
    } else {
        for (int k = tid - 160; k < 100; k += 96) {
            float a = 0.f;
            for (int d = 0; d < 100; ++d) a += sWW[d] * wq[d*100 + k];
            sVQ[k] = a;
        }
        if (tid == 255) {
            float a = 0.f;
            for (int d = 0; d < 100; ++d) a += bq[d] * sWW[d];
            sCq[0] = a;
        }
    }
    __syncthreads();
    // ---- phase2: GPRE (all threads) + QSC + scores ----
    {
        int slot = tid >> 4, k0 = tid & 15;
        #pragma unroll 4
        for (int rp = 0; rp < 25; ++rp) {
            int row = rp*16 + slot;
            const float* wr = wih + row*100;
            float acc = 0.f;
            #pragma unroll
            for (int m = 0; m < 2; ++m) {
                int f4i = k0 + 16*m;
                if (f4i < 25)
                    acc += dot4(*(const float4*)(wr + 4*f4i), *(const float4*)(sET + 4*f4i));
            }
            acc += __shfl_xor(acc, 1); acc += __shfl_xor(acc, 2);
            acc += __shfl_xor(acc, 4); acc += __shfl_xor(acc, 8);
            if (k0 == 0) WS[OFF_GPRE + bt*400 + row] = acc + bih[row] + bhh[row];
        }
    }
    if (tid < 125) {
        int q = tid / 25, j = tid - q*25;
        float4 val = (q == 0) ? *(const float4*)(sEQN + 4*j)
                              : ((const float4*)embS)[(size_t)qsidx[qn*4 + (q-1)]*25 + j];
        *(float4*)(sQSCm + q*100 + 4*j) = val;
        *(float4*)(WS + OFF_QSC + bt*500 + q*100 + 4*j) = val;
    } else if (tid >= 128 && tid < 128 + TS) {
        int tp = tid - 128;
        if (tp < t) {
            int qq = question[b*TT + tp];
            const float* er = embQ + (size_t)qq*100;
            float acc = 0.f;
            #pragma unroll
            for (int k = 0; k < 25; ++k)
                acc += dot4(*(const float4*)(er + 4*k), *(const float4*)(sEQN + 4*k));
            sScore[tp] = acc;
        }
    }
    __syncthreads();
    // ---- phase3: QL (tid<80) + wave-parallel topk (wave 2) ----
    if (tid < 80) {
        int q = tid >> 4, kk = tid & 15;
        float acc = 0.f;
        #pragma unroll
        for (int j = 0; j < 7; ++j) {
            int k = kk + 16*j;
            if (k < 100) acc = fmaf(sQSCm[q*100 + k], sVQ[k], acc);
        }
        acc += __shfl_xor(acc, 1); acc += __shfl_xor(acc, 2);
        acc += __shfl_xor(acc, 4); acc += __shfl_xor(acc, 8);
        if (kk == 0) WS[OFF_QL + bt*8 + q] = acc + sCq[0];
    }
    if (tid >= 128 && tid < 192) {
        int lane = tid - 128;
        int nv = t < 10 ? t : 10;
        int* idxp = (int*)(WS + OFF_IDX) + bt*10;
        if (lane == 0) ((int*)(WS + OFF_NV))[bt] = nv;
        float v = (lane < t) ? sScore[lane] : -3.0e38f;
        int myidx = lane;
        int taken = 0;
        for (int p = 0; p < 10; ++p) {
            float vv = taken ? -3.0e38f : v;
            int ii = myidx;
            #pragma unroll
            for (int m = 1; m < 64; m <<= 1) {
                float v2 = __shfl_xor(vv, m);
                int   i2 = __shfl_xor(ii, m);
                if (v2 > vv || (v2 == vv && i2 < ii)) { vv = v2; ii = i2; }
            }
            if (p < nv) {
                if (lane == 0) idxp[p] = ii;
                if (myidx == ii) taken = 1;
            } else if (lane == 0) idxp[p] = 0;
        }
    }
}

// ================= kseq: 9 waves, 2 barriers/step =================
// SAFETY FIX: hA/hB loaded UNCONDITIONALLY (all threads, converged) — wave 7
// is only partially gated and v_readlane ignores EXEC; loading inside
// `if (isGate)` left lanes 16-63 of wave 7 with garbage registers (the
// R7/R10 flaky-NaN root cause).
__global__ __launch_bounds__(576) void kseq(
    const int* __restrict__ mask, const float* __restrict__ whh,
    const float* __restrict__ wk, const float* __restrict__ bk,
    const float* __restrict__ ww, const float* __restrict__ bwp,
    const float* __restrict__ WS, float* __restrict__ out)
{
    int b = blockIdx.x, tid = threadIdx.x, lane = tid & 63;
    __shared__ __align__(16) float sQSCall[TS*500];
    __shared__ __align__(16) float sSH[TS*PH];
    __shared__ __align__(16) float sQLall[TS*8];
    __shared__ __align__(16) float sVKl[104];
    __shared__ int   sIdxAll[TS*10];
    __shared__ int   sNvAll[TS];
    __shared__ int   sMask[TT];
    __shared__ float sH[104], sC[104], sG[400];
    __shared__ float sKL2[2][12], sGv2[2][64];
    __shared__ float sCk[1];

    size_t b0 = (size_t)b*TS;
    int g = tid - 64;
    bool isGate = (g >= 0 && g < 400);

    float4 wv[25];
    if (isGate) {
        #pragma unroll
        for (int j = 0; j < 25; ++j) wv[j] = *(const float4*)(whh + g*100 + 4*j);
    }
    float gpre = isGate ? WS[OFF_GPRE + b0*400 + g] : 0.f;

    {
        const float4* src = (const float4*)(WS + OFF_QSC + b0*500);
        for (int i4 = tid; i4 < 6125; i4 += 576) ((float4*)sQSCall)[i4] = src[i4];
        const float4* srq = (const float4*)(WS + OFF_QL + b0*8);
        for (int i4 = tid; i4 < 98; i4 += 576) ((float4*)sQLall)[i4] = srq[i4];
    }
    for (int i = tid; i < TS*10;  i += 576) sIdxAll[i] = ((const int*)(WS + OFF_IDX))[b0*10 + i];
    for (int i = tid; i < TS;     i += 576) sNvAll[i]  = ((const int*)(WS + OFF_NV))[b0 + i];
    if (tid < TT) sMask[tid] = mask[b*TT + tid];
    if (tid < 104) { sH[tid] = 0.f; sC[tid] = 0.f; }
    if (tid >= 104 && tid < 204) {
        int k = tid - 104;
        float a = 0.f;
        for (int d = 0; d < 100; ++d) a += ww[100 + d] * wk[d*100 + k];
        sVKl[k] = a;
    }
    if (tid == 204) {
        float a = 0.f;
        for (int d = 0; d < 100; ++d) a += bk[d] * ww[100 + d];
        sCk[0] = a;
    }
    if (tid == 205) out[b*TT] = 0.5f;
    float bw = bwp[0];
    __syncthreads();
    float ck = sCk[0];

    for (int t = 0; t < TS; ++t) {
        int par = t & 1;
        // UNCONDITIONAL h broadcast load — every lane's register valid for readlane
        float hA = sH[lane];
        float hB = sH[64 + (lane % 36)];
        if (isGate) {
            float gpre_nx = 0.f;
            if (t + 1 < TS) gpre_nx = WS[OFF_GPRE + (b0 + t + 1)*400 + g];
            float a0 = 0.f, a1 = 0.f, a2 = 0.f, a3 = 0.f;
            #pragma unroll
            for (int j = 0; j < 25; ++j) {
                const int kb = 4*j;
                float h0, h1, h2, h3;
                if (kb < 64) {
                    h0 = RLF(hA, kb);   h1 = RLF(hA, kb+1);
                    h2 = RLF(hA, kb+2); h3 = RLF(hA, kb+3);
                } else {
                    h0 = RLF(hB, kb-64); h1 = RLF(hB, kb-63);
                    h2 = RLF(hB, kb-62); h3 = RLF(hB, kb-61);
                }
                a0 = fmaf(h0, wv[j].x, a0);
                a1 = fmaf(h1, wv[j].y, a1);
                a2 = fmaf(h2, wv[j].z, a2);
                a3 = fmaf(h3, wv[j].w, a3);
            }
            sG[g] = (a0 + a1) + (a2 + a3) + gpre;
            gpre = gpre_nx;
        } else if (tid >= 512) {
            // wave 8: 60 h-independent dots for step t (float4 LDS reads)
            int nv = sNvAll[t];
            if (lane < 60) {
                bool isKL = lane < 10;
                int s = isKL ? (lane + 1) : (((lane - 10) % 10) + 1);
                int q = isKL ? 0 : ((lane - 10) / 10);
                if (s <= nv) {
                    const float* st = sSH + sIdxAll[t*10 + s - 1]*PH;
                    const float* xp = isKL ? sVKl : (sQSCall + t*500 + q*100);
                    float c0 = 0.f, c1 = 0.f, c2 = 0.f, c3 = 0.f;
                    #pragma unroll
                    for (int j = 0; j < 25; ++j) {
                        float4 a = *(const float4*)(st + 4*j);
                        float4 x = *(const float4*)(xp + 4*j);
                        c0 = fmaf(a.x, x.x, c0);
                        c1 = fmaf(a.y, x.y, c1);
                        c2 = fmaf(a.z, x.z, c2);
                        c3 = fmaf(a.w, x.w, c3);
                    }
                    float acc = (c0 + c1) + (c2 + c3);
                    if (isKL) sKL2[par][s] = acc + ck;
                    else      sGv2[par][q*12 + s] = acc;
                }
            }
        } else if (tid < 64 && t > 0) {
            // wave 0: tail of step t-1
            int tau = t - 1, par2 = tau & 1;
            int nv = sNvAll[tau];
            int dd = lane >> 3, k0 = lane & 7;
            if (dd < 6) {
                const float* xp = (dd == 0) ? sVKl : (sQSCall + tau*500 + (dd-1)*100);
                float acc = 0.f;
                #pragma unroll
                for (int jj = 0; jj < 13; ++jj) {
                    int k = k0 + 8*jj;
                    if (k < 100) acc = fmaf(sH[k], xp[k], acc);
                }
                acc += __shfl_xor(acc, 1); acc += __shfl_xor(acc, 2); acc += __shfl_xor(acc, 4);
                if (k0 == 0) {
                    if (dd == 0) sKL2[par2][0] = acc + ck;
                    else         sGv2[par2][(dd-1)*12] = acc;
                }
            }
            int q = lane / 11, s = lane - q*11;
            bool valid = (lane < 55) && (s <= nv);
            float lg = valid ? (sQLall[tau*8 + q] + sKL2[par2][s] + bw) : 0.f;
            float e  = valid ? __expf(lg) : 0.f;
            float gv = valid ? sGv2[par2][q*12 + s] : 0.f;
            float se = e, sg = e*gv;
            #pragma unroll
            for (int m = 1; m < 64; m <<= 1) { se += __shfl_xor(se, m); sg += __shfl_xor(sg, m); }
            if (lane == 0) out[b*TT + tau + 1] = __fdividef(1.f, 1.f + __expf(-__fdividef(sg, se)));
        }
        __syncthreads();
        if (g >= 0 && g < 100) {
            float gi = sG[g], gf = sG[100+g], gg = sG[200+g], go = sG[300+g];
            float c2 = sigm_fast(gf)*sC[g] + sigm_fast(gi)*tanh_fast(gg);
            float h2 = sigm_fast(go)*tanh_fast(c2);
            if (sMask[t] == 1) { sH[g] = h2; sC[g] = c2; }
            sSH[t*PH + g] = sH[g];
        }
        __syncthreads();
    }
    // epilogue tail: tau = TS-1
    if (tid < 64) {
        int tau = TS - 1, par2 = tau & 1;
        int nv = sNvAll[tau];
        int dd = lane >> 3, k0 = lane & 7;
        if (dd < 6) {
            const float* xp = (dd == 0) ? sVKl : (sQSCall + tau*500 + (dd-1)*100);
            float acc = 0.f;
            #pragma unroll
            for (int jj = 0; jj < 13; ++jj) {
                int k = k0 + 8*jj;
                if (k < 100) acc = fmaf(sH[k], xp[k], acc);
            }
            acc += __shfl_xor(acc, 1); acc += __shfl_xor(acc, 2); acc += __shfl_xor(acc, 4);
            if (k0 == 0) {
                if (dd == 0) sKL2[par2][0] = acc + ck;
                else         sGv2[par2][(dd-1)*12] = acc;
            }
        }
        int q = lane / 11, s = lane - q*11;
        bool valid = (lane < 55) && (s <= nv);
        float lg = valid ? (sQLall[tau*8 + q] + sKL2[par2][s] + bw) : 0.f;
        float e  = valid ? __expf(lg) : 0.f;
        float gv = valid ? sGv2[par2][q*12 + s] : 0.f;
        float se = e, sg = e*gv;
        #pragma unroll
        for (int m = 1; m < 64; m <<= 1) { se += __shfl_xor(se, m); sg += __shfl_xor(sg, m); }
        if (lane == 0) out[b*TT + tau + 1] = __fdividef(1.f, 1.f + __expf(-__fdividef(sg, se)));
    }
}

extern "C" void kernel_launch(void* const* d_in, const int* in_sizes, int n_in,
                              void* d_out, int out_size, void* d_ws, size_t ws_size,
                              hipStream_t stream) {
    const int* user      = (const int*)d_in[0];
    const int* question  = (const int*)d_in[1];
    const int* response  = (const int*)d_in[2];
    const int* mask      = (const int*)d_in[3];
    const int* qnbr      = (const int*)d_in[4];
    const int* snbr      = (const int*)d_in[5];
    const int* unbr      = (const int*)d_in[6];
    const int* qnbr2     = (const int*)d_in[7];
    const int* qsidx     = (const int*)d_in[8];
    const float* embQ    = (const float*)d_in[9];
    const float* embQ2   = (const float*)d_in[10];
    const float* embS    = (const float*)d_in[11];
    const float* embU    = (const float*)d_in[12];
    const float* embR    = (const float*)d_in[13];
    const float* w1      = (const float*)d_in[14];
    const float* w2      = (const float*)d_in[15];
    const float* wih     = (const float*)d_in[16];
    const float* whh     = (const float*)d_in[17];
    const float* bih     = (const float*)d_in[18];
    const float* bhh     = (const float*)d_in[19];
    const float* aggw    = (const float*)d_in[20];
    const float* aggb    = (const float*)d_in[21];
    const float* wlast   = (const float*)d_in[22];
    const float* blast   = (const float*)d_in[23];
    const float* wq      = (const float*)d_in[24];
    const float* bq      = (const float*)d_in[25];
    const float* wk      = (const float*)d_in[26];
    const float* bk      = (const float*)d_in[27];
    const float* ww      = (const float*)d_in[28];
    const float* bwp     = (const float*)d_in[29];
    const float* wfus    = (const float*)d_in[30];
    const float* bfus    = (const float*)d_in[31];
    float* WS = (float*)d_ws;
    float* out = (float*)d_out;

    hipLaunchKernelGGL(kagg, dim3(2*BSZ*TS), dim3(256), 0, stream,
                       user, question, mask, qnbr, snbr, unbr, qnbr2,
                       embQ, embQ2, embS, embU, aggw, aggb, wlast, blast, WS);
    hipLaunchKernelGGL(kfuse, dim3(BSZ*TS), dim3(256), 0, stream,
                       question, response, qsidx, embQ, embS, embR,
                       w1, w2, wfus, bfus, wih, bih, bhh, wq, bq, ww, WS);
    hipLaunchKernelGGL(kseq, dim3(BSZ), dim3(576), 0, stream,
                       mask, whh, wk, bk, ww, bwp, WS, out);
}